// Round 5
// baseline (387.612 us; speedup 1.0000x reference)
//
#include <hip/hip_runtime.h>
#include <cstdint>

typedef __attribute__((ext_vector_type(8))) short short8;
typedef __attribute__((ext_vector_type(4))) float f32x4;

#define NB 16
#define NT 2048
#define ND 1024
#define NC 512
#define NM (NB*NT)   // 32768 rows

#define BM 64        // rows per block
#define BKS 32       // K per stage
#define NSTAGE (ND/BKS)  // 32
#define NWAVE 8      // 512 threads

__device__ __forceinline__ unsigned short f2bf(float f){
  unsigned int u = __float_as_uint(f);
  u += 0x7fffu + ((u >> 16) & 1u);   // RNE; inputs are finite normals
  return (unsigned short)(u >> 16);
}

// async 16B global -> LDS DMA (per-lane global src; wave-uniform LDS base + lane*16)
__device__ __forceinline__ void async_copy16(const void* g, void* l) {
  __builtin_amdgcn_global_load_lds(
      (const __attribute__((address_space(1))) void*)g,
      (__attribute__((address_space(3))) void*)l,
      16, 0, 0);
}

// ---------------- CAM GEMM + fused softmax ----------------
// Block: 512 threads (8 waves), 64 rows x full C=512 (softmax in-block).
//
// B IS NOT STAGED THROUGH LDS. Wt is fragment-ordered (chunk(s,c,q) of 8 bf16
// = Wb[c][s*32+q*8..+8] at elem ((s*512+c)*4+q)*8), so a wave's B-fragment
// for (s,ni) is ONE fully-coalesced 1-KB global_load_dwordx4 into registers
// (lane (quad,lane15) -> chunk lane15*4+quad, dense 1-KB span). W = 1 MB,
// L2-resident on every XCD; loads are register-double-buffered (b0/b1) with
// ~2 stages of slack -> self-pipelining per wave, no barriers, no conflicts.
//
// A (4 KB/stage) is LDS double-buffered via 4 DMA segs (waves 0-3, 1 each)
// from fragment-ordered Ft (built by convert_pool): chunk (mi*16+l15)*4+q.
// ds_read addr = mi*1024B + (lane15*4+quad)*16B: dense 1 KB, conflict-free.
// Counted wait: per stage a wave<4 issues 4 B-loads + 1 A-DMA; at the wait
// point outstanding <= [B(t+1)x4, A(t+1), B(t+2)x4, A(t+2)] -> vmcnt(5)
// guarantees A(t+1) done (in-order), keeps 5 newer ops in flight.
template<bool PRECONV>
__global__ __launch_bounds__(512, 4) void cam_softmax_kernel(
    const unsigned short* __restrict__ Ft,   // bf16 frag-ordered [512][32][2048e]
    const float* __restrict__ F,             // fp32 [32768,1024] (!PRECONV)
    const unsigned short* __restrict__ Wt,   // bf16 frag-ordered [32][512][4][8e]
    float* __restrict__ out_soft,
    float* __restrict__ out_raw)
{
  __shared__ alignas(16) unsigned short As[2][2048];   // 2 x 4 KB
  __shared__ float redmax[NWAVE][BM];
  __shared__ float redsum[NWAVE][BM];

  const int tid    = threadIdx.x;
  const int wave   = tid >> 6;
  const int lane   = tid & 63;
  const int lane15 = lane & 15;
  const int quad   = lane >> 4;
  const int r64    = blockIdx.x;
  const int m0     = r64 * BM;
  const int chunk  = lane15 * 4 + quad;     // 0..63

  // B per-lane base (elements): stage stride 16384, ni stride 512
  const unsigned short* wbase = Wt + wave * 2048 + chunk * 8;

  f32x4 acc[4][4];
  #pragma unroll
  for (int mi = 0; mi < 4; mi++)
    #pragma unroll
    for (int ni = 0; ni < 4; ni++)
      acc[mi][ni] = (f32x4){0.f, 0.f, 0.f, 0.f};

  auto loadB = [&](short8* dst, int s) {
    const unsigned short* p = wbase + s * 16384;
    #pragma unroll
    for (int ni = 0; ni < 4; ni++)
      dst[ni] = *reinterpret_cast<const short8*>(p + ni * 512);
  };
  auto stageA = [&](int s, int buf) {
    if (wave < 4)
      async_copy16(Ft + ((size_t)r64 * 32 + s) * 2048 + wave * 512 + lane * 8,
                   &As[buf][wave * 512]);
  };
  auto compute = [&](int buf, const short8* bf) {
    short8 af[4];
    #pragma unroll
    for (int mi = 0; mi < 4; mi++)
      af[mi] = *reinterpret_cast<const short8*>(&As[buf][mi * 512 + chunk * 8]);
    #pragma unroll
    for (int ni = 0; ni < 4; ni++)
      #pragma unroll
      for (int mi = 0; mi < 4; mi++)
        acc[mi][ni] = __builtin_amdgcn_mfma_f32_16x16x32_bf16(
            af[mi], bf[ni], acc[mi][ni], 0, 0, 0);
  };

  if (PRECONV) {
    short8 b0[4], b1[4];
    // ---- prologue: A(0),B(0),A(1),B(1) in flight; publish tile 0 ----
    stageA(0, 0);
    loadB(b0, 0);
    stageA(1, 1);
    loadB(b1, 1);
    if (wave < 4) asm volatile("s_waitcnt vmcnt(9)" ::: "memory"); // A(0) done
    __builtin_amdgcn_s_barrier();

    #pragma unroll 1
    for (int t = 0; t < NSTAGE; t += 2) {
      // ---- even phase: tile t (buf0, b0) ----
      __builtin_amdgcn_s_setprio(1);
      compute(0, b0);
      __builtin_amdgcn_s_setprio(0);
      if (t + 2 < NSTAGE) loadB(b0, t + 2);
      __builtin_amdgcn_s_barrier();            // all waves done reading As[0]
      if (t + 2 < NSTAGE) {
        stageA(t + 2, 0);
        if (wave < 4) asm volatile("s_waitcnt vmcnt(5)" ::: "memory"); // A(t+1)
      } else {
        if (wave < 4) asm volatile("s_waitcnt vmcnt(0)" ::: "memory");
      }
      __builtin_amdgcn_s_barrier();            // As[1] (tile t+1) published

      // ---- odd phase: tile t+1 (buf1, b1) ----
      __builtin_amdgcn_s_setprio(1);
      compute(1, b1);
      __builtin_amdgcn_s_setprio(0);
      if (t + 3 < NSTAGE) loadB(b1, t + 3);
      __builtin_amdgcn_s_barrier();            // all waves done reading As[1]
      if (t + 3 < NSTAGE) {
        stageA(t + 3, 1);
        if (wave < 4) asm volatile("s_waitcnt vmcnt(5)" ::: "memory"); // A(t+2)
      }
      __builtin_amdgcn_s_barrier();            // As[0] (tile t+2) published
    }
  } else {
    // ---- fallback: build As from F fp32 per stage (drain loop) ----
    for (int s = 0; s < NSTAGE; s++) {
      if (tid < 256) {
        const int q = tid & 3, l15 = (tid >> 2) & 15, mi = tid >> 6;
        const int row = mi * 16 + l15;
        const float* src = F + (size_t)(m0 + row) * ND + s * 32 + q * 8;
        const float4 v0 = *reinterpret_cast<const float4*>(src);
        const float4 v1 = *reinterpret_cast<const float4*>(src + 4);
        ushort4 a, b;
        a.x = f2bf(v0.x); a.y = f2bf(v0.y); a.z = f2bf(v0.z); a.w = f2bf(v0.w);
        b.x = f2bf(v1.x); b.y = f2bf(v1.y); b.z = f2bf(v1.z); b.w = f2bf(v1.w);
        unsigned short* d = &As[0][(row * 4 + q) * 8];
        *reinterpret_cast<ushort4*>(d)     = a;
        *reinterpret_cast<ushort4*>(d + 4) = b;
      }
      __syncthreads();
      short8 bl[4];
      loadB(bl, s);
      compute(0, bl);
      __syncthreads();
    }
  }

  // ---- epilogue: fused softmax over C=512 ----
  // C/D layout: col = lane15 (+wave*64+ni*16), row = quad*4 + reg (+mi*16)
  #pragma unroll
  for (int mi = 0; mi < 4; mi++)
    #pragma unroll
    for (int r = 0; r < 4; r++) {
      float m = acc[mi][0][r];
      #pragma unroll
      for (int ni = 1; ni < 4; ni++) m = fmaxf(m, acc[mi][ni][r]);
      #pragma unroll
      for (int off = 1; off < 16; off <<= 1) m = fmaxf(m, __shfl_xor(m, off, 64));
      if (lane15 == 0) redmax[wave][mi * 16 + quad * 4 + r] = m;
    }
  __syncthreads();

  float rsum[4][4];
  #pragma unroll
  for (int mi = 0; mi < 4; mi++)
    #pragma unroll
    for (int r = 0; r < 4; r++) {
      const int row = mi * 16 + quad * 4 + r;
      float m = redmax[0][row];
      #pragma unroll
      for (int w = 1; w < NWAVE; w++) m = fmaxf(m, redmax[w][row]);
      float s = 0.f;
      #pragma unroll
      for (int ni = 0; ni < 4; ni++) {
        const float e = __expf(acc[mi][ni][r] - m);
        acc[mi][ni][r] = e;
        s += e;
      }
      #pragma unroll
      for (int off = 1; off < 16; off <<= 1) s += __shfl_xor(s, off, 64);
      rsum[mi][r] = s;
    }
  if (lane15 == 0) {
    #pragma unroll
    for (int mi = 0; mi < 4; mi++)
      #pragma unroll
      for (int r = 0; r < 4; r++)
        redsum[wave][mi * 16 + quad * 4 + r] = rsum[mi][r];
  }
  __syncthreads();

  #pragma unroll
  for (int mi = 0; mi < 4; mi++)
    #pragma unroll
    for (int r = 0; r < 4; r++) {
      const int row = mi * 16 + quad * 4 + r;
      float s = redsum[0][row];
      #pragma unroll
      for (int w = 1; w < NWAVE; w++) s += redsum[w][row];
      const float inv = 1.f / s;
      const size_t gr = (size_t)(m0 + row) * NC;
      #pragma unroll
      for (int ni = 0; ni < 4; ni++) {
        const int col = wave * 64 + ni * 16 + lane15;
        const float v = acc[mi][ni][r] * inv;
        out_soft[gr + col] = v;
        out_raw [gr + col] = v;
      }
    }
}

// ---------------- convert(+pool): F fp32 -> Ft bf16 frag-ordered, row-tile partials ----
// grid 512 blocks (one 64-row tile r64 each), 512 threads.
// thread t: q = t&3, s = (t>>2)&31, g(=mi) = t>>7; iterates j(=l15) 0..15.
// reads F[row][s*32+q*8..+8] (coalesced float8), writes Ft chunk ((g*16+j)*4+q).
template<bool WRITE_FT>
__global__ __launch_bounds__(512) void convert_pool_kernel(
    const float* __restrict__ F, unsigned short* __restrict__ Ft,
    float* __restrict__ part)    // part[512][1024]
{
  __shared__ float psum[4 * ND];   // 16 KB
  const int tid = threadIdx.x;
  const int r64 = blockIdx.x;
  const int q   = tid & 3;
  const int s   = (tid >> 2) & 31;
  const int g   = tid >> 7;
  const int d0  = s * 32 + q * 8;

  const size_t srcbase = ((size_t)r64 * 64 + g * 16) * ND + d0;
  const size_t dstbase = ((size_t)r64 * 32 + s) * 2048 + (size_t)g * 512 + q * 8;

  float p[8];
  #pragma unroll
  for (int e = 0; e < 8; e++) p[e] = 0.f;

  #pragma unroll 4
  for (int j = 0; j < 16; j++) {
    const float* src = F + srcbase + (size_t)j * ND;
    const float4 v0 = *reinterpret_cast<const float4*>(src);
    const float4 v1 = *reinterpret_cast<const float4*>(src + 4);
    if (WRITE_FT) {
      ushort4 a, b;
      a.x = f2bf(v0.x); a.y = f2bf(v0.y); a.z = f2bf(v0.z); a.w = f2bf(v0.w);
      b.x = f2bf(v1.x); b.y = f2bf(v1.y); b.z = f2bf(v1.z); b.w = f2bf(v1.w);
      unsigned short* d = Ft + dstbase + j * 32;
      *reinterpret_cast<ushort4*>(d)     = a;
      *reinterpret_cast<ushort4*>(d + 4) = b;
    }
    p[0] += v0.x; p[1] += v0.y; p[2] += v0.z; p[3] += v0.w;
    p[4] += v1.x; p[5] += v1.y; p[6] += v1.z; p[7] += v1.w;
  }
  float* ps = &psum[g * ND + d0];
  #pragma unroll
  for (int e = 0; e < 8; e++) ps[e] = p[e];
  __syncthreads();
  if (tid < 256) {
    const int d4 = tid * 4;
    float4 r;
    r.x = psum[d4 + 0] + psum[ND + d4 + 0] + psum[2 * ND + d4 + 0] + psum[3 * ND + d4 + 0];
    r.y = psum[d4 + 1] + psum[ND + d4 + 1] + psum[2 * ND + d4 + 1] + psum[3 * ND + d4 + 1];
    r.z = psum[d4 + 2] + psum[ND + d4 + 2] + psum[2 * ND + d4 + 2] + psum[3 * ND + d4 + 2];
    r.w = psum[d4 + 3] + psum[ND + d4 + 3] + psum[2 * ND + d4 + 3] + psum[3 * ND + d4 + 3];
    *reinterpret_cast<float4*>(part + (size_t)r64 * ND + d4) = r;
  }
}

// ---------------- W fp32 -> Wt bf16 fragment-ordered ----------------
// chunk g: q = g&3, c = (g>>2)&511, s = g>>11; Wt[g*8..+8] = bf16(W[c][s*32+q*8..+8])
__global__ __launch_bounds__(256) void convw_kernel(
    const float* __restrict__ W, unsigned short* __restrict__ Wt)
{
  const int g = blockIdx.x * 256 + threadIdx.x;   // 0..65535
  const int q = g & 3, c = (g >> 2) & 511, s = g >> 11;
  const float* src = W + (size_t)c * ND + s * 32 + q * 8;
  const float4 a = *reinterpret_cast<const float4*>(src);
  const float4 b = *reinterpret_cast<const float4*>(src + 4);
  ushort4 lo, hi;
  lo.x = f2bf(a.x); lo.y = f2bf(a.y); lo.z = f2bf(a.z); lo.w = f2bf(a.w);
  hi.x = f2bf(b.x); hi.y = f2bf(b.y); hi.z = f2bf(b.z); hi.w = f2bf(b.w);
  *reinterpret_cast<ushort4*>(Wt + (size_t)g * 8)     = lo;
  *reinterpret_cast<ushort4*>(Wt + (size_t)g * 8 + 4) = hi;
}

// ---------------- logits = pooled @ W^T + b (fp32) ----------------
__global__ __launch_bounds__(512) void logits_kernel(
    const float* __restrict__ part, const float* __restrict__ W,
    const float* __restrict__ bias, float* __restrict__ out_logits)
{
  __shared__ float p[ND];
  const int b = blockIdx.x;
  const int tid = threadIdx.x;
  for (int i = tid; i < ND; i += 512) {
    float s = 0.f;
    #pragma unroll
    for (int z = 0; z < 32; z++) s += part[(size_t)(b * 32 + z) * ND + i];
    p[i] = s * (1.f / NT);
  }
  __syncthreads();
  const int c = tid;
  const float* wr = W + (size_t)c * ND;
  float s = 0.f;
  #pragma unroll 4
  for (int k = 0; k < ND; k++) s = fmaf(p[k], wr[k], s);
  out_logits[b * NC + c] = s + bias[c];
}

// ---------------- cross-entropy loss (fp32, wave-parallel) ----------------
__global__ __launch_bounds__(512) void loss_kernel(
    const float* __restrict__ logits, const int* __restrict__ labels,
    float* __restrict__ out_loss)
{
  __shared__ float term[16];
  const int tid  = threadIdx.x;
  const int wave = tid >> 6;
  const int lane = tid & 63;
  #pragma unroll
  for (int k = 0; k < 2; k++) {
    const int b = wave + k * 8;
    float v[8];
    float m = -3.4e38f;
    #pragma unroll
    for (int j = 0; j < 8; j++) {
      v[j] = logits[b * NC + j * 64 + lane];
      m = fmaxf(m, v[j]);
    }
    #pragma unroll
    for (int off = 1; off < 64; off <<= 1) m = fmaxf(m, __shfl_xor(m, off, 64));
    float e = 0.f;
    #pragma unroll
    for (int j = 0; j < 8; j++) e += expf(v[j] - m);
    #pragma unroll
    for (int off = 1; off < 64; off <<= 1) e += __shfl_xor(e, off, 64);
    if (lane == 0) {
      const int lab = labels[b];
      term[b] = -(logits[b * NC + lab] - m - logf(e));
    }
  }
  __syncthreads();
  if (tid == 0) {
    float a = 0.f;
    #pragma unroll
    for (int b = 0; b < 16; b++) a += term[b];
    out_loss[0] = a * (1.f / NB);
  }
}

extern "C" void kernel_launch(void* const* d_in, const int* in_sizes, int n_in,
                              void* d_out, int out_size, void* d_ws, size_t ws_size,
                              hipStream_t stream) {
  const float* F      = (const float*)d_in[0];   // [16,2048,1024]
  const int*   labels = (const int*)  d_in[1];   // [16]
  const float* W      = (const float*)d_in[2];   // [512,1024]
  const float* bias   = (const float*)d_in[3];   // [512]

  float* out        = (float*)d_out;
  float* out_soft   = out;
  float* out_raw    = out + (size_t)NM * NC;
  float* out_logits = out + (size_t)2 * NM * NC;
  float* out_loss   = out_logits + (size_t)NB * NC;

  // ws layout: part [0, 2 MiB) | Wt [2 MiB, 3 MiB) | Ft [4 MiB, 68 MiB)
  char* ws = (char*)d_ws;
  float* part = (float*)ws;                                     // 512*1024 f32
  unsigned short* Wt = (unsigned short*)(ws + (2u << 20));      // 32*512*4*8 bf16
  unsigned short* Ft = (unsigned short*)(ws + (4u << 20));      // 512*32*2048 bf16
  const bool preconv = ws_size >= (4u << 20) + (size_t)NM * ND * 2;

  convw_kernel<<<NC * ND / (256 * 8), 256, 0, stream>>>(W, Wt);
  if (preconv) {
    convert_pool_kernel<true><<<NM / BM, 512, 0, stream>>>(F, Ft, part);
    cam_softmax_kernel<true><<<NM / BM, 512, 0, stream>>>(Ft, F, Wt, out_soft, out_raw);
  } else {
    convert_pool_kernel<false><<<NM / BM, 512, 0, stream>>>(F, Ft, part);
    cam_softmax_kernel<false><<<NM / BM, 512, 0, stream>>>(Ft, F, Wt, out_soft, out_raw);
  }
  logits_kernel<<<NB, 512, 0, stream>>>(part, W, bias, out_logits);
  loss_kernel<<<1, 512, 0, stream>>>(out_logits, labels, out_loss);
}

// Round 6
// 314.933 us; speedup vs baseline: 1.2308x; 1.2308x over previous
//
#include <hip/hip_runtime.h>
#include <cstdint>

typedef __attribute__((ext_vector_type(8))) short short8;
typedef __attribute__((ext_vector_type(4))) float f32x4;

#define NB 16
#define NT 2048
#define ND 1024
#define NC 512
#define NM (NB*NT)   // 32768 rows

#define BM 64        // rows per block
#define BKS 32       // K per stage
#define NSTAGE (ND/BKS)  // 32
#define NWAVE 8      // 512 threads

__device__ __forceinline__ unsigned short f2bf(float f){
  unsigned int u = __float_as_uint(f);
  u += 0x7fffu + ((u >> 16) & 1u);   // RNE; inputs are finite normals
  return (unsigned short)(u >> 16);
}

// async 16B global -> LDS DMA (per-lane global src; wave-uniform LDS base + lane*16)
__device__ __forceinline__ void async_copy16(const void* g, void* l) {
  __builtin_amdgcn_global_load_lds(
      (const __attribute__((address_space(1))) void*)g,
      (__attribute__((address_space(3))) void*)l,
      16, 0, 0);
}

// ---------------- CAM GEMM + fused softmax ----------------
// Block: 512 threads (8 waves), 64 rows x full C=512 (softmax in-block).
//
// B IS NOT STAGED THROUGH LDS. Wt is fragment-ordered (chunk(s,c,q) of 8 bf16
// = Wb[c][s*32+q*8..+8] at elem ((s*512+c)*4+q)*8), so a wave's B-fragment
// for (s,ni) is ONE fully-coalesced 1-KB global_load_dwordx4 into registers
// (lane (quad,lane15) -> chunk lane15*4+quad, dense 1-KB span). W = 1 MB,
// L2-resident on every XCD; loads are register-double-buffered (b0/b1) with
// ~2 stages of slack -> self-pipelining per wave, no barriers, no conflicts.
//
// A (4 KB/stage) is LDS double-buffered via 4 DMA segs (waves 0-3, 1 each)
// from fragment-ordered Ft (built by convert_pool): chunk (mi*16+l15)*4+q.
// ds_read addr = mi*1024B + (lane15*4+quad)*16B: dense 1 KB, conflict-free.
// Counted wait: per stage a wave<4 issues 4 B-loads + 1 A-DMA; at the wait
// point outstanding <= [B(t+1)x4, A(t+1), B(t+2)x4, A(t+2)] -> vmcnt(5)
// guarantees A(t+1) done (in-order), keeps 5 newer ops in flight.
template<bool PRECONV>
__global__ __launch_bounds__(512, 4) void cam_softmax_kernel(
    const unsigned short* __restrict__ Ft,   // bf16 frag-ordered [512][32][2048e]
    const float* __restrict__ F,             // fp32 [32768,1024] (!PRECONV)
    const unsigned short* __restrict__ Wt,   // bf16 frag-ordered [32][512][4][8e]
    float* __restrict__ out_soft,
    float* __restrict__ out_raw)
{
  __shared__ alignas(16) unsigned short As[2][2048];   // 2 x 4 KB
  __shared__ float redmax[NWAVE][BM];
  __shared__ float redsum[NWAVE][BM];

  const int tid    = threadIdx.x;
  const int wave   = tid >> 6;
  const int lane   = tid & 63;
  const int lane15 = lane & 15;
  const int quad   = lane >> 4;
  const int r64    = blockIdx.x;
  const int m0     = r64 * BM;
  const int chunk  = lane15 * 4 + quad;     // 0..63

  // B per-lane base (elements): stage stride 16384, ni stride 512
  const unsigned short* wbase = Wt + wave * 2048 + chunk * 8;

  f32x4 acc[4][4];
  #pragma unroll
  for (int mi = 0; mi < 4; mi++)
    #pragma unroll
    for (int ni = 0; ni < 4; ni++)
      acc[mi][ni] = (f32x4){0.f, 0.f, 0.f, 0.f};

  auto loadB = [&](short8* dst, int s) {
    const unsigned short* p = wbase + s * 16384;
    #pragma unroll
    for (int ni = 0; ni < 4; ni++)
      dst[ni] = *reinterpret_cast<const short8*>(p + ni * 512);
  };
  auto stageA = [&](int s, int buf) {
    if (wave < 4)
      async_copy16(Ft + ((size_t)r64 * 32 + s) * 2048 + wave * 512 + lane * 8,
                   &As[buf][wave * 512]);
  };
  auto compute = [&](int buf, const short8* bf) {
    short8 af[4];
    #pragma unroll
    for (int mi = 0; mi < 4; mi++)
      af[mi] = *reinterpret_cast<const short8*>(&As[buf][mi * 512 + chunk * 8]);
    #pragma unroll
    for (int ni = 0; ni < 4; ni++)
      #pragma unroll
      for (int mi = 0; mi < 4; mi++)
        acc[mi][ni] = __builtin_amdgcn_mfma_f32_16x16x32_bf16(
            af[mi], bf[ni], acc[mi][ni], 0, 0, 0);
  };

  if (PRECONV) {
    short8 b0[4], b1[4];
    // ---- prologue: A(0),B(0),A(1),B(1) in flight; publish tile 0 ----
    stageA(0, 0);
    loadB(b0, 0);
    stageA(1, 1);
    loadB(b1, 1);
    if (wave < 4) asm volatile("s_waitcnt vmcnt(9)" ::: "memory"); // A(0) done
    __builtin_amdgcn_s_barrier();

    #pragma unroll 1
    for (int t = 0; t < NSTAGE; t += 2) {
      // ---- even phase: tile t (buf0, b0) ----
      __builtin_amdgcn_s_setprio(1);
      compute(0, b0);
      __builtin_amdgcn_s_setprio(0);
      if (t + 2 < NSTAGE) loadB(b0, t + 2);
      __builtin_amdgcn_s_barrier();            // all waves done reading As[0]
      if (t + 2 < NSTAGE) {
        stageA(t + 2, 0);
        if (wave < 4) asm volatile("s_waitcnt vmcnt(5)" ::: "memory"); // A(t+1)
      } else {
        if (wave < 4) asm volatile("s_waitcnt vmcnt(0)" ::: "memory");
      }
      __builtin_amdgcn_s_barrier();            // As[1] (tile t+1) published

      // ---- odd phase: tile t+1 (buf1, b1) ----
      __builtin_amdgcn_s_setprio(1);
      compute(1, b1);
      __builtin_amdgcn_s_setprio(0);
      if (t + 3 < NSTAGE) loadB(b1, t + 3);
      __builtin_amdgcn_s_barrier();            // all waves done reading As[1]
      if (t + 3 < NSTAGE) {
        stageA(t + 3, 1);
        if (wave < 4) asm volatile("s_waitcnt vmcnt(5)" ::: "memory"); // A(t+2)
      }
      __builtin_amdgcn_s_barrier();            // As[0] (tile t+2) published
    }
  } else {
    // ---- fallback: build As from F fp32 per stage (drain loop) ----
    for (int s = 0; s < NSTAGE; s++) {
      if (tid < 256) {
        const int q = tid & 3, l15 = (tid >> 2) & 15, mi = tid >> 6;
        const int row = mi * 16 + l15;
        const float* src = F + (size_t)(m0 + row) * ND + s * 32 + q * 8;
        const float4 v0 = *reinterpret_cast<const float4*>(src);
        const float4 v1 = *reinterpret_cast<const float4*>(src + 4);
        ushort4 a, b;
        a.x = f2bf(v0.x); a.y = f2bf(v0.y); a.z = f2bf(v0.z); a.w = f2bf(v0.w);
        b.x = f2bf(v1.x); b.y = f2bf(v1.y); b.z = f2bf(v1.z); b.w = f2bf(v1.w);
        unsigned short* d = &As[0][(row * 4 + q) * 8];
        *reinterpret_cast<ushort4*>(d)     = a;
        *reinterpret_cast<ushort4*>(d + 4) = b;
      }
      __syncthreads();
      short8 bl[4];
      loadB(bl, s);
      compute(0, bl);
      __syncthreads();
    }
  }

  // ---- epilogue: fused softmax over C=512 ----
  // C/D layout: col = lane15 (+wave*64+ni*16), row = quad*4 + reg (+mi*16)
  #pragma unroll
  for (int mi = 0; mi < 4; mi++)
    #pragma unroll
    for (int r = 0; r < 4; r++) {
      float m = acc[mi][0][r];
      #pragma unroll
      for (int ni = 1; ni < 4; ni++) m = fmaxf(m, acc[mi][ni][r]);
      #pragma unroll
      for (int off = 1; off < 16; off <<= 1) m = fmaxf(m, __shfl_xor(m, off, 64));
      if (lane15 == 0) redmax[wave][mi * 16 + quad * 4 + r] = m;
    }
  __syncthreads();

  float rsum[4][4];
  #pragma unroll
  for (int mi = 0; mi < 4; mi++)
    #pragma unroll
    for (int r = 0; r < 4; r++) {
      const int row = mi * 16 + quad * 4 + r;
      float m = redmax[0][row];
      #pragma unroll
      for (int w = 1; w < NWAVE; w++) m = fmaxf(m, redmax[w][row]);
      float s = 0.f;
      #pragma unroll
      for (int ni = 0; ni < 4; ni++) {
        const float e = __expf(acc[mi][ni][r] - m);
        acc[mi][ni][r] = e;
        s += e;
      }
      #pragma unroll
      for (int off = 1; off < 16; off <<= 1) s += __shfl_xor(s, off, 64);
      rsum[mi][r] = s;
    }
  if (lane15 == 0) {
    #pragma unroll
    for (int mi = 0; mi < 4; mi++)
      #pragma unroll
      for (int r = 0; r < 4; r++)
        redsum[wave][mi * 16 + quad * 4 + r] = rsum[mi][r];
  }
  __syncthreads();

  #pragma unroll
  for (int mi = 0; mi < 4; mi++)
    #pragma unroll
    for (int r = 0; r < 4; r++) {
      const int row = mi * 16 + quad * 4 + r;
      float s = redsum[0][row];
      #pragma unroll
      for (int w = 1; w < NWAVE; w++) s += redsum[w][row];
      const float inv = 1.f / s;
      const size_t gr = (size_t)(m0 + row) * NC;
      #pragma unroll
      for (int ni = 0; ni < 4; ni++) {
        const int col = wave * 64 + ni * 16 + lane15;
        const float v = acc[mi][ni][r] * inv;
        out_soft[gr + col] = v;
        out_raw [gr + col] = v;
      }
    }
}

// ---------------- convert(+pool): F fp32 -> Ft bf16 frag-ordered, row-tile partials ----
// grid 512 blocks (one 64-row tile r64 each), 512 threads.
// thread t: q = t&3, s = (t>>2)&31, g(=mi) = t>>7; iterates j(=l15) 0..15.
// reads F[row][s*32+q*8..+8] (coalesced float8), writes Ft chunk ((g*16+j)*4+q).
template<bool WRITE_FT>
__global__ __launch_bounds__(512) void convert_pool_kernel(
    const float* __restrict__ F, unsigned short* __restrict__ Ft,
    float* __restrict__ part)    // part[512][1024]
{
  __shared__ float psum[4 * ND];   // 16 KB
  const int tid = threadIdx.x;
  const int r64 = blockIdx.x;
  const int q   = tid & 3;
  const int s   = (tid >> 2) & 31;
  const int g   = tid >> 7;
  const int d0  = s * 32 + q * 8;

  const size_t srcbase = ((size_t)r64 * 64 + g * 16) * ND + d0;
  const size_t dstbase = ((size_t)r64 * 32 + s) * 2048 + (size_t)g * 512 + q * 8;

  float p[8];
  #pragma unroll
  for (int e = 0; e < 8; e++) p[e] = 0.f;

  #pragma unroll 4
  for (int j = 0; j < 16; j++) {
    const float* src = F + srcbase + (size_t)j * ND;
    const float4 v0 = *reinterpret_cast<const float4*>(src);
    const float4 v1 = *reinterpret_cast<const float4*>(src + 4);
    if (WRITE_FT) {
      ushort4 a, b;
      a.x = f2bf(v0.x); a.y = f2bf(v0.y); a.z = f2bf(v0.z); a.w = f2bf(v0.w);
      b.x = f2bf(v1.x); b.y = f2bf(v1.y); b.z = f2bf(v1.z); b.w = f2bf(v1.w);
      unsigned short* d = Ft + dstbase + j * 32;
      *reinterpret_cast<ushort4*>(d)     = a;
      *reinterpret_cast<ushort4*>(d + 4) = b;
    }
    p[0] += v0.x; p[1] += v0.y; p[2] += v0.z; p[3] += v0.w;
    p[4] += v1.x; p[5] += v1.y; p[6] += v1.z; p[7] += v1.w;
  }
  float* ps = &psum[g * ND + d0];
  #pragma unroll
  for (int e = 0; e < 8; e++) ps[e] = p[e];
  __syncthreads();
  if (tid < 256) {
    const int d4 = tid * 4;
    float4 r;
    r.x = psum[d4 + 0] + psum[ND + d4 + 0] + psum[2 * ND + d4 + 0] + psum[3 * ND + d4 + 0];
    r.y = psum[d4 + 1] + psum[ND + d4 + 1] + psum[2 * ND + d4 + 1] + psum[3 * ND + d4 + 1];
    r.z = psum[d4 + 2] + psum[ND + d4 + 2] + psum[2 * ND + d4 + 2] + psum[3 * ND + d4 + 2];
    r.w = psum[d4 + 3] + psum[ND + d4 + 3] + psum[2 * ND + d4 + 3] + psum[3 * ND + d4 + 3];
    *reinterpret_cast<float4*>(part + (size_t)r64 * ND + d4) = r;
  }
}

// ---------------- W fp32 -> Wt bf16 fragment-ordered ----------------
// chunk g: q = g&3, c = (g>>2)&511, s = g>>11; Wt[g*8..+8] = bf16(W[c][s*32+q*8..+8])
__global__ __launch_bounds__(256) void convw_kernel(
    const float* __restrict__ W, unsigned short* __restrict__ Wt)
{
  const int g = blockIdx.x * 256 + threadIdx.x;   // 0..65535
  const int q = g & 3, c = (g >> 2) & 511, s = g >> 11;
  const float* src = W + (size_t)c * ND + s * 32 + q * 8;
  const float4 a = *reinterpret_cast<const float4*>(src);
  const float4 b = *reinterpret_cast<const float4*>(src + 4);
  ushort4 lo, hi;
  lo.x = f2bf(a.x); lo.y = f2bf(a.y); lo.z = f2bf(a.z); lo.w = f2bf(a.w);
  hi.x = f2bf(b.x); hi.y = f2bf(b.y); hi.z = f2bf(b.z); hi.w = f2bf(b.w);
  *reinterpret_cast<ushort4*>(Wt + (size_t)g * 8)     = lo;
  *reinterpret_cast<ushort4*>(Wt + (size_t)g * 8 + 4) = hi;
}

// ---------------- logits = pooled @ W^T + b (fp32, parallel) ----------------
// grid (8 c-groups, 16 b), 512 threads = 64 c-lanes x 8 k-groups.
// Old version: 16 blocks, per-thread SERIAL 1024-iter dependent fmaf chain
// with scalar loads -> 89 us at 1.4% occupancy, 0.4% VALUBusy (latency-bound).
// Now: chain length 128, float4 W loads, 128 blocks, LDS tree reduce.
__global__ __launch_bounds__(512) void logits_kernel(
    const float* __restrict__ part, const float* __restrict__ W,
    const float* __restrict__ bias, float* __restrict__ out_logits)
{
  __shared__ float p[ND];          // pooled vector for this b (4 KB)
  __shared__ float red[8][64];     // k-group partials (2 KB)
  const int b   = blockIdx.y;
  const int cg  = blockIdx.x;
  const int tid = threadIdx.x;

  // pooled: each thread sums 2 columns over the 32 part rows of batch b
  for (int i = tid; i < ND; i += 512) {
    float s = 0.f;
    #pragma unroll
    for (int z = 0; z < 32; z++) s += part[(size_t)(b * 32 + z) * ND + i];
    p[i] = s * (1.f / NT);
  }
  __syncthreads();

  const int cl = tid & 63;         // c within group
  const int kg = tid >> 6;         // k-group 0..7 (128 k each)
  const int c  = cg * 64 + cl;
  const float* wr = W + (size_t)c * ND + kg * 128;
  const float* pk = p + kg * 128;
  float s = 0.f;
  #pragma unroll
  for (int k4 = 0; k4 < 32; k4++) {
    const float4 wv = *reinterpret_cast<const float4*>(wr + k4 * 4);
    s = fmaf(pk[k4 * 4 + 0], wv.x, s);
    s = fmaf(pk[k4 * 4 + 1], wv.y, s);
    s = fmaf(pk[k4 * 4 + 2], wv.z, s);
    s = fmaf(pk[k4 * 4 + 3], wv.w, s);
  }
  red[kg][cl] = s;
  __syncthreads();
  if (tid < 64) {
    float t = 0.f;
    #pragma unroll
    for (int g = 0; g < 8; g++) t += red[g][tid];
    out_logits[b * NC + cg * 64 + tid] = t + bias[cg * 64 + tid];
  }
}

// ---------------- cross-entropy loss (fp32, wave-parallel) ----------------
__global__ __launch_bounds__(512) void loss_kernel(
    const float* __restrict__ logits, const int* __restrict__ labels,
    float* __restrict__ out_loss)
{
  __shared__ float term[16];
  const int tid  = threadIdx.x;
  const int wave = tid >> 6;
  const int lane = tid & 63;
  #pragma unroll
  for (int k = 0; k < 2; k++) {
    const int b = wave + k * 8;
    float v[8];
    float m = -3.4e38f;
    #pragma unroll
    for (int j = 0; j < 8; j++) {
      v[j] = logits[b * NC + j * 64 + lane];
      m = fmaxf(m, v[j]);
    }
    #pragma unroll
    for (int off = 1; off < 64; off <<= 1) m = fmaxf(m, __shfl_xor(m, off, 64));
    float e = 0.f;
    #pragma unroll
    for (int j = 0; j < 8; j++) e += expf(v[j] - m);
    #pragma unroll
    for (int off = 1; off < 64; off <<= 1) e += __shfl_xor(e, off, 64);
    if (lane == 0) {
      const int lab = labels[b];
      term[b] = -(logits[b * NC + lab] - m - logf(e));
    }
  }
  __syncthreads();
  if (tid == 0) {
    float a = 0.f;
    #pragma unroll
    for (int b = 0; b < 16; b++) a += term[b];
    out_loss[0] = a * (1.f / NB);
  }
}

extern "C" void kernel_launch(void* const* d_in, const int* in_sizes, int n_in,
                              void* d_out, int out_size, void* d_ws, size_t ws_size,
                              hipStream_t stream) {
  const float* F      = (const float*)d_in[0];   // [16,2048,1024]
  const int*   labels = (const int*)  d_in[1];   // [16]
  const float* W      = (const float*)d_in[2];   // [512,1024]
  const float* bias   = (const float*)d_in[3];   // [512]

  float* out        = (float*)d_out;
  float* out_soft   = out;
  float* out_raw    = out + (size_t)NM * NC;
  float* out_logits = out + (size_t)2 * NM * NC;
  float* out_loss   = out_logits + (size_t)NB * NC;

  // ws layout: part [0, 2 MiB) | Wt [2 MiB, 3 MiB) | Ft [4 MiB, 68 MiB)
  char* ws = (char*)d_ws;
  float* part = (float*)ws;                                     // 512*1024 f32
  unsigned short* Wt = (unsigned short*)(ws + (2u << 20));      // 32*512*4*8 bf16
  unsigned short* Ft = (unsigned short*)(ws + (4u << 20));      // 512*32*2048 bf16
  const bool preconv = ws_size >= (4u << 20) + (size_t)NM * ND * 2;

  convw_kernel<<<NC * ND / (256 * 8), 256, 0, stream>>>(W, Wt);
  if (preconv) {
    convert_pool_kernel<true><<<NM / BM, 512, 0, stream>>>(F, Ft, part);
    cam_softmax_kernel<true><<<NM / BM, 512, 0, stream>>>(Ft, F, Wt, out_soft, out_raw);
  } else {
    convert_pool_kernel<false><<<NM / BM, 512, 0, stream>>>(F, Ft, part);
    cam_softmax_kernel<false><<<NM / BM, 512, 0, stream>>>(Ft, F, Wt, out_soft, out_raw);
  }
  logits_kernel<<<dim3(8, NB), 512, 0, stream>>>(part, W, bias, out_logits);
  loss_kernel<<<1, 512, 0, stream>>>(out_logits, labels, out_loss);
}